// Round 2
// baseline (119.023 us; speedup 1.0000x reference)
//
#include <hip/hip_runtime.h>
#include <stdint.h>

// BS=16, T=16, N=512, C=128, E=128, OUT=256; P=8192, BT=256
// square[b,t,n,c] = feats[b, n*T+t, c]
// x1[e][bt][c] = sum_n square[n][c]*eig[e][n]          (bf16, ws)
// x3[bt][o][e] = sum_c x1[e][bt][c]*paramT[e][o][c]    (bf16, ws)
// out[bt][n][o] = relu(sum_e x3[bt][o][e]*eigT[n][e])  (f32, d_out)

typedef short bf16x8 __attribute__((ext_vector_type(8)));
typedef float f32x4 __attribute__((ext_vector_type(4)));

__device__ __forceinline__ ushort f2bf(float x) {
  uint32_t u = __float_as_uint(x);
  u += 0x7fffu + ((u >> 16) & 1u);
  return (ushort)(u >> 16);
}

// ---------------- prep: eig -> bf16 [e][n] and transposed [n][e] ----------------
__global__ __launch_bounds__(128) void k_prep_eig(const float* __restrict__ eig,
                                                  ushort* __restrict__ eig_bf,
                                                  ushort* __restrict__ eigT) {
  int bid = blockIdx.x, t = threadIdx.x;
  if (bid < 512) {
    int n = bid;
    eigT[n * 128 + t] = f2bf(eig[t * 512 + n]);
  } else {
    int e = bid - 512;
#pragma unroll
    for (int i = 0; i < 4; ++i) {
      int n = t + i * 128;
      eig_bf[e * 512 + n] = f2bf(eig[e * 512 + n]);
    }
  }
}

// ---------------- prep: paramT[e][o][c] = bf16(param[o][c][e]) ----------------
__global__ __launch_bounds__(256) void k_prep_param(const float* __restrict__ param,
                                                    ushort* __restrict__ paramT) {
  int o = blockIdx.x;
  int c = threadIdx.x & 127, h = threadIdx.x >> 7;
#pragma unroll 4
  for (int ee = 0; ee < 64; ++ee) {
    int e = h * 64 + ee;
    paramT[(size_t)e * 32768 + o * 128 + c] = f2bf(param[(size_t)o * 16384 + c * 128 + e]);
  }
}

// ---------------- stage 1: x1[e][bt][c] ----------------
// grid 512: (bt, c-half). LDS only for feats transpose; eig B-frags direct from global.
__global__ __launch_bounds__(256) void k_stage1(const float* __restrict__ feats,
                                                const ushort* __restrict__ eig_bf,
                                                ushort* __restrict__ x1) {
  int bid = blockIdx.x;
  int bt = bid >> 1, ch = bid & 1;
  int b = bt >> 4, tt = bt & 15;
  __shared__ ushort As[64 * 72];  // [c-local 64][n-chunk 64 pad 72]
  int tid = threadIdx.x, l = tid & 63, w = tid >> 6;
  int lr = l & 15, lg = l >> 4;
  int wr = (w & 1) * 32;   // c-local offset (2 waves cover 64 c)
  int wc = (w >> 1) * 64;  // e offset (2 waves cover 128 e)
  f32x4 acc[2][4] = {};
  const float* fbase = feats + (size_t)b * (8192 * 128) + (size_t)tt * 128 + ch * 64;

  for (int nc = 0; nc < 8; ++nc) {
    int n0 = nc * 64;
    // transpose feats chunk into As[c][n]
    {
      int nl = w * 16 + lr;  // 0..63
      int cg = lg * 4;       // 0,4,8,12
      const float* rowp = fbase + (size_t)(n0 + nl) * 2048;  // row stride 16*128 floats
#pragma unroll
      for (int i = 0; i < 4; ++i) {
        int c0 = cg + i * 16;
        float4 v = *(const float4*)(rowp + c0);
        As[(c0 + 0) * 72 + nl] = f2bf(v.x);
        As[(c0 + 1) * 72 + nl] = f2bf(v.y);
        As[(c0 + 2) * 72 + nl] = f2bf(v.z);
        As[(c0 + 3) * 72 + nl] = f2bf(v.w);
      }
    }
    __syncthreads();
#pragma unroll
    for (int kk = 0; kk < 64; kk += 32) {
      bf16x8 af[2], bg[4];
#pragma unroll
      for (int fm = 0; fm < 2; ++fm)
        af[fm] = *(const bf16x8*)&As[(wr + fm * 16 + lr) * 72 + kk + lg * 8];
#pragma unroll
      for (int fn = 0; fn < 4; ++fn)
        bg[fn] = *(const bf16x8*)&eig_bf[(size_t)(wc + fn * 16 + lr) * 512 + n0 + kk + lg * 8];
#pragma unroll
      for (int fm = 0; fm < 2; ++fm)
#pragma unroll
        for (int fn = 0; fn < 4; ++fn)
          acc[fm][fn] = __builtin_amdgcn_mfma_f32_16x16x32_bf16(af[fm], bg[fn], acc[fm][fn], 0, 0, 0);
    }
    __syncthreads();
  }
  // epilogue: x1[e][bt][c] 8B packed
#pragma unroll
  for (int fm = 0; fm < 2; ++fm) {
    int c = ch * 64 + wr + fm * 16 + lg * 4;
#pragma unroll
    for (int fn = 0; fn < 4; ++fn) {
      int e = wc + fn * 16 + lr;
      ushort4 pk;
      pk.x = f2bf(acc[fm][fn][0]);
      pk.y = f2bf(acc[fm][fn][1]);
      pk.z = f2bf(acc[fm][fn][2]);
      pk.w = f2bf(acc[fm][fn][3]);
      *(ushort4*)(x1 + (size_t)e * 32768 + bt * 128 + c) = pk;
    }
  }
}

// ---------------- stage 2: x3[bt][o][e] ----------------
// No LDS, no syncs: MFMA operands as direct per-lane b128 global loads (L1/L2-served).
// 512 blocks; XCD swizzle groups all e-blocks of the same (btb,ob) pair per XCD.
__global__ __launch_bounds__(256) void k_stage2(const ushort* __restrict__ x1,
                                                const ushort* __restrict__ paramT,
                                                ushort* __restrict__ x3) {
  int bid = blockIdx.x;
  int logical = (bid & 7) * 64 + (bid >> 3);  // bijective: 512 % 8 == 0
  int pair = logical >> 5, eg = logical & 31;
  int btb = pair >> 2, ob = pair & 3;
  int bt0 = btb * 64, o0 = ob * 64, e0 = eg * 4;
  int tid = threadIdx.x, l = tid & 63, w = tid >> 6;
  int lr = l & 15, lg = l >> 4;
  int wbt = (w & 1) * 32, wo = (w >> 1) * 32;

  float res[2][2][4][4];
#pragma unroll
  for (int ei = 0; ei < 4; ++ei) {
    int e = e0 + ei;
    const ushort* pa = x1 + (size_t)e * 32768;
    const ushort* pb = paramT + (size_t)e * 32768;
    f32x4 acc[2][2] = {};
#pragma unroll
    for (int kk = 0; kk < 128; kk += 32) {
      bf16x8 af[2], bg[2];
#pragma unroll
      for (int fm = 0; fm < 2; ++fm)
        af[fm] = *(const bf16x8*)&pa[(bt0 + wbt + fm * 16 + lr) * 128 + kk + lg * 8];
#pragma unroll
      for (int fn = 0; fn < 2; ++fn)
        bg[fn] = *(const bf16x8*)&pb[(o0 + wo + fn * 16 + lr) * 128 + kk + lg * 8];
#pragma unroll
      for (int fm = 0; fm < 2; ++fm)
#pragma unroll
        for (int fn = 0; fn < 2; ++fn)
          acc[fm][fn] = __builtin_amdgcn_mfma_f32_16x16x32_bf16(af[fm], bg[fn], acc[fm][fn], 0, 0, 0);
    }
#pragma unroll
    for (int fm = 0; fm < 2; ++fm)
#pragma unroll
      for (int fn = 0; fn < 2; ++fn)
#pragma unroll
        for (int r = 0; r < 4; ++r) res[fm][fn][r][ei] = acc[fm][fn][r];
  }
#pragma unroll
  for (int fm = 0; fm < 2; ++fm) {
    int btl = bt0 + wbt + fm * 16 + lg * 4;
#pragma unroll
    for (int fn = 0; fn < 2; ++fn) {
      int o = o0 + wo + fn * 16 + lr;
#pragma unroll
      for (int r = 0; r < 4; ++r) {
        ushort4 pk;
        pk.x = f2bf(res[fm][fn][r][0]);
        pk.y = f2bf(res[fm][fn][r][1]);
        pk.z = f2bf(res[fm][fn][r][2]);
        pk.w = f2bf(res[fm][fn][r][3]);
        *(ushort4*)(x3 + (size_t)(btl + r) * 32768 + o * 128 + e0) = pk;
      }
    }
  }
}

// ---------------- stage 3: out = relu(x3 @ eigT^T) ----------------
// No LDS: x3 rows (o, K=e contig) and eigT rows (n, K=e contig) direct b128 loads.
// 2048 blocks; XCD swizzle: each XCD owns 32 consecutive bt (x3 slices L2-resident).
__global__ __launch_bounds__(256) void k_stage3(const ushort* __restrict__ x3,
                                                const ushort* __restrict__ eigT,
                                                float* __restrict__ out) {
  int bid = blockIdx.x;
  int logical = (bid & 7) * 256 + (bid >> 3);  // 2048 % 8 == 0
  int bt = logical >> 3, ob = (logical >> 2) & 1, nb = logical & 3;
  int o0 = ob * 128, n0 = nb * 128;
  int tid = threadIdx.x, l = tid & 63, w = tid >> 6;
  int lr = l & 15, lg = l >> 4;
  int wo = (w & 1) * 64, wn = (w >> 1) * 64;
  f32x4 acc[4][4] = {};
  const ushort* pa = x3 + (size_t)bt * 32768;

#pragma unroll
  for (int ck = 0; ck < 4; ++ck) {
    int kk = ck * 32;
    bf16x8 af[4], bg[4];
#pragma unroll
    for (int fm = 0; fm < 4; ++fm)
      af[fm] = *(const bf16x8*)&pa[(o0 + wo + fm * 16 + lr) * 128 + kk + lg * 8];
#pragma unroll
    for (int fn = 0; fn < 4; ++fn)
      bg[fn] = *(const bf16x8*)&eigT[(size_t)(n0 + wn + fn * 16 + lr) * 128 + kk + lg * 8];
#pragma unroll
    for (int fm = 0; fm < 4; ++fm)
#pragma unroll
      for (int fn = 0; fn < 4; ++fn)
        acc[fm][fn] = __builtin_amdgcn_mfma_f32_16x16x32_bf16(af[fm], bg[fn], acc[fm][fn], 0, 0, 0);
  }
#pragma unroll
  for (int fm = 0; fm < 4; ++fm) {
    int o = o0 + wo + fm * 16 + lg * 4;
#pragma unroll
    for (int fn = 0; fn < 4; ++fn) {
      int n = n0 + wn + fn * 16 + lr;
      float4 v;
      v.x = fmaxf(acc[fm][fn][0], 0.f);
      v.y = fmaxf(acc[fm][fn][1], 0.f);
      v.z = fmaxf(acc[fm][fn][2], 0.f);
      v.w = fmaxf(acc[fm][fn][3], 0.f);
      *(float4*)(out + (size_t)bt * 131072 + (size_t)n * 256 + o) = v;
    }
  }
}

extern "C" void kernel_launch(void* const* d_in, const int* in_sizes, int n_in,
                              void* d_out, int out_size, void* d_ws, size_t ws_size,
                              hipStream_t stream) {
  const float* feats = (const float*)d_in[0];
  const float* eig = (const float*)d_in[4];
  const float* param = (const float*)d_in[5];
  float* out = (float*)d_out;

  char* ws = (char*)d_ws;
  ushort* paramT = (ushort*)(ws);                 // 8 MB  [e][o][c]
  ushort* eig_bf = (ushort*)(ws + 8388608);       // 128 KB [e][n]
  ushort* eigT   = (ushort*)(ws + 8519680);       // 128 KB [n][e]
  ushort* x1     = (ushort*)(ws + 8650752);       // 8 MB  [e][bt][c]
  ushort* x3     = (ushort*)(ws + 17039360);      // 16 MB [bt][o][e]

  hipLaunchKernelGGL(k_prep_eig, dim3(640), dim3(128), 0, stream, eig, eig_bf, eigT);
  hipLaunchKernelGGL(k_prep_param, dim3(256), dim3(256), 0, stream, param, paramT);
  hipLaunchKernelGGL(k_stage1, dim3(512), dim3(256), 0, stream, feats, eig_bf, x1);
  hipLaunchKernelGGL(k_stage2, dim3(512), dim3(256), 0, stream, x1, paramT, x3);
  hipLaunchKernelGGL(k_stage3, dim3(2048), dim3(256), 0, stream, x3, eigT, out);
}

// Round 3
// 105.158 us; speedup vs baseline: 1.1319x; 1.1319x over previous
//
#include <hip/hip_runtime.h>
#include <stdint.h>

// BS=16, T=16, N=512, C=128, E=128, OUT=256; P=8192, BT=256
// square[b,t,n,c] = feats[b, n*T+t, c]
// x1[e][bt][c] = sum_n square[n][c]*eig[e][n]          (bf16, ws)
// x3[bt][o][e] = sum_c x1[e][bt][c]*paramT[e][o][c]    (bf16, ws)
// out[bt][n][o] = relu(sum_e x3[bt][o][e]*eigT[n][e])  (f32, d_out)

typedef short bf16x8 __attribute__((ext_vector_type(8)));
typedef float f32x4 __attribute__((ext_vector_type(4)));

__device__ __forceinline__ ushort f2bf(float x) {
  uint32_t u = __float_as_uint(x);
  u += 0x7fffu + ((u >> 16) & 1u);
  return (ushort)(u >> 16);
}

// ---------------- prep: eig -> bf16 [e][n] and transposed [n][e] ----------------
__global__ __launch_bounds__(128) void k_prep_eig(const float* __restrict__ eig,
                                                  ushort* __restrict__ eig_bf,
                                                  ushort* __restrict__ eigT) {
  int bid = blockIdx.x, t = threadIdx.x;
  if (bid < 512) {
    int n = bid;
    eigT[n * 128 + t] = f2bf(eig[t * 512 + n]);
  } else {
    int e = bid - 512;
#pragma unroll
    for (int i = 0; i < 4; ++i) {
      int n = t + i * 128;
      eig_bf[e * 512 + n] = f2bf(eig[e * 512 + n]);
    }
  }
}

// ---------------- prep: paramT[e][o][c] = bf16(param[o][c][e]) ----------------
__global__ __launch_bounds__(256) void k_prep_param(const float* __restrict__ param,
                                                    ushort* __restrict__ paramT) {
  int o = blockIdx.x;
  int c = threadIdx.x & 127, h = threadIdx.x >> 7;
#pragma unroll 4
  for (int ee = 0; ee < 64; ++ee) {
    int e = h * 64 + ee;
    paramT[(size_t)e * 32768 + o * 128 + c] = f2bf(param[(size_t)o * 16384 + c * 128 + e]);
  }
}

// ---------------- stage 1: x1[e][bt][c] ----------------
// grid 512: (bt, c-half); 2 blocks/CU so staging latency overlaps across blocks.
// Both operands through LDS (R1-proven structure).
__global__ __launch_bounds__(256) void k_stage1(const float* __restrict__ feats,
                                                const ushort* __restrict__ eig_bf,
                                                ushort* __restrict__ x1) {
  int bid = blockIdx.x;
  int bt = bid >> 1, ch = bid & 1;
  int b = bt >> 4, tt = bt & 15;
  __shared__ ushort As[64 * 72];   // [c-local 64][n-chunk 64 pad 72]
  __shared__ ushort Bs[128 * 72];  // [e 128][n-chunk 64 pad 72]
  int tid = threadIdx.x, l = tid & 63, w = tid >> 6;
  int lr = l & 15, lg = l >> 4;
  int wr = (w & 1) * 32;   // c-local offset (2 waves x 32)
  int wc = (w >> 1) * 64;  // e offset (2 waves x 64)
  f32x4 acc[2][4] = {};
  const float* fbase = feats + (size_t)b * (8192 * 128) + (size_t)tt * 128 + ch * 64;

  for (int nc = 0; nc < 8; ++nc) {
    int n0 = nc * 64;
    // transpose feats chunk into As[c][n]
    {
      int nl = w * 16 + lr;  // 0..63
      int cg = lg * 4;       // 0,4,8,12
      const float* rowp = fbase + (size_t)(n0 + nl) * 2048;
#pragma unroll
      for (int i = 0; i < 4; ++i) {
        int c0 = cg + i * 16;
        float4 v = *(const float4*)(rowp + c0);
        As[(c0 + 0) * 72 + nl] = f2bf(v.x);
        As[(c0 + 1) * 72 + nl] = f2bf(v.y);
        As[(c0 + 2) * 72 + nl] = f2bf(v.z);
        As[(c0 + 3) * 72 + nl] = f2bf(v.w);
      }
    }
    // eig rows (linear copy, L2-resident source)
    {
      int part = tid & 7;
      int er = tid >> 3;
#pragma unroll
      for (int p = 0; p < 4; ++p) {
        int e = er + p * 32;
        uint4 v = *(const uint4*)(eig_bf + (size_t)e * 512 + n0 + part * 8);
        *(uint4*)&Bs[e * 72 + part * 8] = v;
      }
    }
    __syncthreads();
#pragma unroll
    for (int kk = 0; kk < 64; kk += 32) {
      bf16x8 af[2], bg[4];
#pragma unroll
      for (int fm = 0; fm < 2; ++fm)
        af[fm] = *(const bf16x8*)&As[(wr + fm * 16 + lr) * 72 + kk + lg * 8];
#pragma unroll
      for (int fn = 0; fn < 4; ++fn)
        bg[fn] = *(const bf16x8*)&Bs[(wc + fn * 16 + lr) * 72 + kk + lg * 8];
#pragma unroll
      for (int fm = 0; fm < 2; ++fm)
#pragma unroll
        for (int fn = 0; fn < 4; ++fn)
          acc[fm][fn] = __builtin_amdgcn_mfma_f32_16x16x32_bf16(af[fm], bg[fn], acc[fm][fn], 0, 0, 0);
    }
    __syncthreads();
  }
  // epilogue: x1[e][bt][c] 8B packed
#pragma unroll
  for (int fm = 0; fm < 2; ++fm) {
    int c = ch * 64 + wr + fm * 16 + lg * 4;
#pragma unroll
    for (int fn = 0; fn < 4; ++fn) {
      int e = wc + fn * 16 + lr;
      ushort4 pk;
      pk.x = f2bf(acc[fm][fn][0]);
      pk.y = f2bf(acc[fm][fn][1]);
      pk.z = f2bf(acc[fm][fn][2]);
      pk.w = f2bf(acc[fm][fn][3]);
      *(ushort4*)(x1 + (size_t)e * 32768 + bt * 128 + c) = pk;
    }
  }
}

// ---------------- stage 2: x3[bt][o][e] ----------------
// grid 256: (btb 0..3) x (ob 0..3) x (ec 0..15). XCD swizzle groups SAME-ec blocks
// (which share x1/paramT e-slices) onto one XCD: per-XCD working set = 16 e-slices
// = 2MB x1 + 2MB paramT -> fits 4MB L2, each slice fetched once from HBM.
__global__ __launch_bounds__(256) void k_stage2(const ushort* __restrict__ x1,
                                                const ushort* __restrict__ paramT,
                                                ushort* __restrict__ x3) {
  int bid = blockIdx.x;
  int l_ = (bid & 7) * 32 + (bid >> 3);  // bijective, 256 % 8 == 0
  int btb = l_ & 3, ob = (l_ >> 2) & 3, ec = l_ >> 4;
  int bt0 = btb * 64, o0 = ob * 64, e0 = ec * 8;
  __shared__ ushort As[64 * 136];  // [bt][c pad 136]
  __shared__ ushort Bs[64 * 136];  // [o][c pad 136]
  int tid = threadIdx.x, l = tid & 63, w = tid >> 6;
  int wbt = (w & 1) * 32, wo = (w >> 1) * 32;
  int lr = l & 15, lg = l >> 4;

#pragma unroll
  for (int eh = 0; eh < 2; ++eh) {
    float res[2][2][4][4];
#pragma unroll
    for (int ei = 0; ei < 4; ++ei) {
      int e = e0 + eh * 4 + ei;
      {
        int part = tid & 15, row = tid >> 4;
#pragma unroll
        for (int p = 0; p < 4; ++p) {
          int r_ = row + p * 16;
          uint4 va = *(const uint4*)(x1 + (size_t)e * 32768 + (bt0 + r_) * 128 + part * 8);
          *(uint4*)&As[r_ * 136 + part * 8] = va;
          uint4 vb = *(const uint4*)(paramT + (size_t)e * 32768 + (o0 + r_) * 128 + part * 8);
          *(uint4*)&Bs[r_ * 136 + part * 8] = vb;
        }
      }
      __syncthreads();
      f32x4 acc[2][2] = {};
#pragma unroll
      for (int kk = 0; kk < 128; kk += 32) {
        bf16x8 af[2], bg[2];
#pragma unroll
        for (int fm = 0; fm < 2; ++fm)
          af[fm] = *(const bf16x8*)&As[(wbt + fm * 16 + lr) * 136 + kk + lg * 8];
#pragma unroll
        for (int fn = 0; fn < 2; ++fn)
          bg[fn] = *(const bf16x8*)&Bs[(wo + fn * 16 + lr) * 136 + kk + lg * 8];
#pragma unroll
        for (int fm = 0; fm < 2; ++fm)
#pragma unroll
          for (int fn = 0; fn < 2; ++fn)
            acc[fm][fn] = __builtin_amdgcn_mfma_f32_16x16x32_bf16(af[fm], bg[fn], acc[fm][fn], 0, 0, 0);
      }
      __syncthreads();
#pragma unroll
      for (int fm = 0; fm < 2; ++fm)
#pragma unroll
        for (int fn = 0; fn < 2; ++fn)
#pragma unroll
          for (int r = 0; r < 4; ++r) res[fm][fn][r][ei] = acc[fm][fn][r];
    }
#pragma unroll
    for (int fm = 0; fm < 2; ++fm) {
      int btl = bt0 + wbt + fm * 16 + lg * 4;
#pragma unroll
      for (int fn = 0; fn < 2; ++fn) {
        int o = o0 + wo + fn * 16 + lr;
#pragma unroll
        for (int r = 0; r < 4; ++r) {
          ushort4 pk;
          pk.x = f2bf(res[fm][fn][r][0]);
          pk.y = f2bf(res[fm][fn][r][1]);
          pk.z = f2bf(res[fm][fn][r][2]);
          pk.w = f2bf(res[fm][fn][r][3]);
          *(ushort4*)(x3 + (size_t)(btl + r) * 32768 + o * 128 + e0 + eh * 4) = pk;
        }
      }
    }
  }
}

// ---------------- stage 3: out = relu(x3 @ eigT^T) ----------------
// grid 2048; XCD swizzle groups the 8 blocks sharing one bt (x3 slice 64KB) per XCD.
__global__ __launch_bounds__(256) void k_stage3(const ushort* __restrict__ x3,
                                                const ushort* __restrict__ eigT,
                                                float* __restrict__ out) {
  int bid = blockIdx.x;
  int l_ = (bid & 7) * 256 + (bid >> 3);  // bijective, 2048 % 8 == 0
  int bt = l_ >> 3, ob = (l_ >> 2) & 1, nb = l_ & 3;
  int o0 = ob * 128, n0 = nb * 128;
  __shared__ ushort As[128 * 72];  // [o][e-chunk 64 pad 72]
  __shared__ ushort Bs[128 * 72];  // [n][e-chunk 64 pad 72]
  int tid = threadIdx.x, l = tid & 63, w = tid >> 6;
  int lr = l & 15, lg = l >> 4;
  int wo = (w & 1) * 64, wn = (w >> 1) * 64;
  f32x4 acc[4][4] = {};

#pragma unroll
  for (int ch = 0; ch < 2; ++ch) {
    int e0 = ch * 64;
    {
      int part = tid & 7, row = tid >> 3;
#pragma unroll
      for (int p = 0; p < 4; ++p) {
        int r_ = row + p * 32;
        uint4 va = *(const uint4*)(x3 + (size_t)bt * 32768 + (o0 + r_) * 128 + e0 + part * 8);
        *(uint4*)&As[r_ * 72 + part * 8] = va;
        uint4 vb = *(const uint4*)(eigT + (size_t)(n0 + r_) * 128 + e0 + part * 8);
        *(uint4*)&Bs[r_ * 72 + part * 8] = vb;
      }
    }
    __syncthreads();
#pragma unroll
    for (int kk = 0; kk < 64; kk += 32) {
      bf16x8 af[4], bg[4];
#pragma unroll
      for (int fm = 0; fm < 4; ++fm)
        af[fm] = *(const bf16x8*)&As[(wo + fm * 16 + lr) * 72 + kk + lg * 8];
#pragma unroll
      for (int fn = 0; fn < 4; ++fn)
        bg[fn] = *(const bf16x8*)&Bs[(wn + fn * 16 + lr) * 72 + kk + lg * 8];
#pragma unroll
      for (int fm = 0; fm < 4; ++fm)
#pragma unroll
        for (int fn = 0; fn < 4; ++fn)
          acc[fm][fn] = __builtin_amdgcn_mfma_f32_16x16x32_bf16(af[fm], bg[fn], acc[fm][fn], 0, 0, 0);
    }
    __syncthreads();
  }
#pragma unroll
  for (int fm = 0; fm < 4; ++fm) {
    int o = o0 + wo + fm * 16 + lg * 4;
#pragma unroll
    for (int fn = 0; fn < 4; ++fn) {
      int n = n0 + wn + fn * 16 + lr;
      float4 v;
      v.x = fmaxf(acc[fm][fn][0], 0.f);
      v.y = fmaxf(acc[fm][fn][1], 0.f);
      v.z = fmaxf(acc[fm][fn][2], 0.f);
      v.w = fmaxf(acc[fm][fn][3], 0.f);
      *(float4*)(out + (size_t)bt * 131072 + (size_t)n * 256 + o) = v;
    }
  }
}

extern "C" void kernel_launch(void* const* d_in, const int* in_sizes, int n_in,
                              void* d_out, int out_size, void* d_ws, size_t ws_size,
                              hipStream_t stream) {
  const float* feats = (const float*)d_in[0];
  const float* eig = (const float*)d_in[4];
  const float* param = (const float*)d_in[5];
  float* out = (float*)d_out;

  char* ws = (char*)d_ws;
  ushort* paramT = (ushort*)(ws);                 // 8 MB  [e][o][c]
  ushort* eig_bf = (ushort*)(ws + 8388608);       // 128 KB [e][n]
  ushort* eigT   = (ushort*)(ws + 8519680);       // 128 KB [n][e]
  ushort* x1     = (ushort*)(ws + 8650752);       // 8 MB  [e][bt][c]
  ushort* x3     = (ushort*)(ws + 17039360);      // 16 MB [bt][o][e]

  hipLaunchKernelGGL(k_prep_eig, dim3(640), dim3(128), 0, stream, eig, eig_bf, eigT);
  hipLaunchKernelGGL(k_prep_param, dim3(256), dim3(256), 0, stream, param, paramT);
  hipLaunchKernelGGL(k_stage1, dim3(512), dim3(256), 0, stream, feats, eig_bf, x1);
  hipLaunchKernelGGL(k_stage2, dim3(256), dim3(256), 0, stream, x1, paramT, x3);
  hipLaunchKernelGGL(k_stage3, dim3(2048), dim3(256), 0, stream, x3, eigT, out);
}